// Round 5
// baseline (260.049 us; speedup 1.0000x reference)
//
#include <hip/hip_runtime.h>

typedef unsigned short u16;
typedef unsigned int u32;
typedef __attribute__((ext_vector_type(8))) short bh8;   // 8 x bf16 raw bits
typedef __attribute__((ext_vector_type(4))) float fx4;
typedef __attribute__((ext_vector_type(4))) short s4;

#define QS 0.2550437194342803f   /* (1/sqrt(32)) * log2(e) */

__device__ __forceinline__ u16 f2bf(float f) {
    unsigned u = __float_as_uint(f);
    u += 0x7fffu + ((u >> 16) & 1u);   // round-to-nearest-even
    return (u16)(u >> 16);
}

// ------------------------------------------------------------------
// prep: x -> bf16 (vectorized copy); all weights transposed via tiled
// 64x64 LDS transpose (coalesced global reads AND writes); fused QKV
// weight/bias with Q side pre-scaled by QS (softmax in exp2 domain).
// grid = 128 (x) + 1 (bias) + 304 transpose tiles = 433 blocks
// ------------------------------------------------------------------
__global__ __launch_bounds__(256) void prep_kernel(
    const float* x, const float* ew1, const float* ew2, const float* gw,
    const float* wq, const float* wk, const float* wv, const float* wo,
    const float* w1, const float* w2,
    const float* bq, const float* bk, const float* bv,
    u16* xb, u16* ew1t, u16* ew2t, u16* gwt,
    u16* wqkvt, float* bqkv, u16* wot, u16* w1t, u16* w2t)
{
    __shared__ u16 tile[64 * 65];
    int bid = blockIdx.x;
    const int t = threadIdx.x;

    if (bid < 128) {   // x convert: 1M floats
        const float4* x4 = (const float4*)x;
        s4* o4 = (s4*)xb;
        #pragma unroll
        for (int i = 0; i < 8; i++) {
            int fi = bid * 2048 + i * 256 + t;
            float4 v = x4[fi];
            s4 o = { (short)f2bf(v.x), (short)f2bf(v.y), (short)f2bf(v.z), (short)f2bf(v.w) };
            o4[fi] = o;
        }
        return;
    }
    bid -= 128;
    if (bid < 1) {     // bqkv [2][384]
        for (int idx = t; idx < 768; idx += 256) {
            int l = idx / 384, n = idx % 384;
            float v;
            if (n < 128)      v = bq[l * 128 + n] * QS;
            else if (n < 256) v = bk[l * 128 + n - 128];
            else              v = bv[l * 128 + n - 256];
            bqkv[idx] = v;
        }
        return;
    }
    bid -= 1;

    const float* src; u16* dst; int R, C, tr, tc; float sc = 1.f;
    if (bid < 8)            { src = ew1; dst = ew1t; R = 256; C = 128; tr = bid >> 1; tc = bid & 1; }
    else if ((bid -= 8) < 4)  { src = ew2; dst = ew2t; R = 128; C = 128; tr = bid >> 1; tc = bid & 1; }
    else if ((bid -= 4) < 4)  { src = gw;  dst = gwt;  R = 128; C = 128; tr = bid >> 1; tc = bid & 1; }
    else if ((bid -= 4) < 24) {
        int l = bid / 12, r2 = bid % 12, which = r2 >> 2, i = r2 & 3;
        R = 128; C = 128; tr = i >> 1; tc = i & 1;
        if (which == 0)      { src = wq + l * 16384; dst = wqkvt + l * 49152;         sc = QS; }
        else if (which == 1) { src = wk + l * 16384; dst = wqkvt + l * 49152 + 16384; }
        else                 { src = wv + l * 16384; dst = wqkvt + l * 49152 + 32768; }
    }
    else if ((bid -= 24) < 8)   { int l = bid >> 2, i = bid & 3;  src = wo + l * 16384; dst = wot + l * 16384; R = 128; C = 128; tr = i >> 1; tc = i & 1; }
    else if ((bid -= 8) < 128)  { int l = bid >> 6, i = bid & 63; src = w1 + (size_t)l * 262144; dst = w1t + (size_t)l * 262144; R = 128;  C = 2048; tr = i & 1;  tc = i >> 1; }
    else { bid -= 128;            int l = bid >> 6, i = bid & 63; src = w2 + (size_t)l * 262144; dst = w2t + (size_t)l * 262144; R = 2048; C = 128;  tr = i >> 1; tc = i & 1; }

    // transpose 64x64 tile: dst[(tc*64+c)*R + tr*64 + r] = src[(tr*64+r)*C + tc*64 + c]
    const int r = t >> 2, cs = (t & 3) * 16;
    const float* sp = src + (size_t)(tr * 64 + r) * C + tc * 64 + cs;
    #pragma unroll
    for (int j = 0; j < 16; j++) tile[r * 65 + cs + j] = f2bf(sp[j] * sc);
    __syncthreads();
    u16* dp = dst + (size_t)(tc * 64 + r) * R + tr * 64 + cs;
    #pragma unroll
    for (int j = 0; j < 16; j++) dp[j] = tile[(cs + j) * 65 + r];
}

// ------------------------------------------------------------------
// templated staged bf16 MFMA GEMM: C[M,N] = A[M,K] @ Bt[N,K]^T
// BM x BN tile, 4 waves in 2x2, each wave BM/2 x BN/2 (NMxNN fragments
// of 16x16x32). Double-buffered LDS, ONE barrier per K-step, register
// prefetch issued post-barrier, ds_write at end of step.
// split-K via blockIdx.z/kchunk -> f32 partial to Cpart.
// Cvt: cols >=256 written transposed (V of the QKV GEMM).
// ------------------------------------------------------------------
template<int BM, int BN>
__global__ __launch_bounds__(256) void gemm_t(
    const u16* __restrict__ A, const u16* __restrict__ Bt,
    const float* __restrict__ bias,
    float* __restrict__ Cf, u16* __restrict__ Cb, float* __restrict__ Cpart,
    u16* __restrict__ Cvt,
    int M, int N, int K, int relu, int kchunk, int ldc)
{
    constexpr int NM = BM / 32, NN = BN / 32;
    constexpr int ASL = BM * 4, BSL = BN * 4;            // int4 slots/buffer
    constexpr int ANI = (ASL + 255) / 256, BNI = (BSL + 255) / 256;
    __shared__ __align__(16) u16 As[2][BM][40];
    __shared__ __align__(16) u16 Bs[2][BN][40];
    const int m0 = blockIdx.x * BM, n0 = blockIdx.y * BN, z = blockIdx.z;
    const int tid = threadIdx.x;
    const int lane = tid & 63, w = tid >> 6;
    const int wm = (w >> 1) * (BM / 2), wn = (w & 1) * (BN / 2);
    const int l15 = lane & 15, l4 = lane >> 4;
    const int k0 = z * kchunk;

    fx4 acc[NM][NN] = {};

    #pragma unroll
    for (int i = 0; i < ANI; i++) { int s = tid + i * 256; if (s < ASL) { int r = s >> 2, c = (s & 3) * 8; *(int4*)&As[0][r][c] = *(const int4*)&A[(size_t)(m0 + r) * K + k0 + c]; } }
    #pragma unroll
    for (int i = 0; i < BNI; i++) { int s = tid + i * 256; if (s < BSL) { int r = s >> 2, c = (s & 3) * 8; *(int4*)&Bs[0][r][c] = *(const int4*)&Bt[(size_t)(n0 + r) * K + k0 + c]; } }

    const int niter = kchunk >> 5;
    for (int it = 0; it < niter; it++) {
        const int cur = it & 1;
        int4 ar[ANI], br[BNI];
        __syncthreads();
        if (it + 1 < niter) {
            #pragma unroll
            for (int i = 0; i < ANI; i++) { int s = tid + i * 256; if (s < ASL) { int r = s >> 2, c = (s & 3) * 8; ar[i] = *(const int4*)&A[(size_t)(m0 + r) * K + k0 + (it + 1) * 32 + c]; } }
            #pragma unroll
            for (int i = 0; i < BNI; i++) { int s = tid + i * 256; if (s < BSL) { int r = s >> 2, c = (s & 3) * 8; br[i] = *(const int4*)&Bt[(size_t)(n0 + r) * K + k0 + (it + 1) * 32 + c]; } }
        }
        bh8 af[NM], bf[NN];
        #pragma unroll
        for (int mi = 0; mi < NM; mi++) af[mi] = *(const bh8*)&As[cur][wm + mi * 16 + l15][l4 * 8];
        #pragma unroll
        for (int nj = 0; nj < NN; nj++) bf[nj] = *(const bh8*)&Bs[cur][wn + nj * 16 + l15][l4 * 8];
        #pragma unroll
        for (int mi = 0; mi < NM; mi++)
            #pragma unroll
            for (int nj = 0; nj < NN; nj++)
                acc[mi][nj] = __builtin_amdgcn_mfma_f32_16x16x32_bf16(af[mi], bf[nj], acc[mi][nj], 0, 0, 0);
        if (it + 1 < niter) {
            #pragma unroll
            for (int i = 0; i < ANI; i++) { int s = tid + i * 256; if (s < ASL) { int r = s >> 2, c = (s & 3) * 8; *(int4*)&As[cur ^ 1][r][c] = ar[i]; } }
            #pragma unroll
            for (int i = 0; i < BNI; i++) { int s = tid + i * 256; if (s < BSL) { int r = s >> 2, c = (s & 3) * 8; *(int4*)&Bs[cur ^ 1][r][c] = br[i]; } }
        }
    }

    #pragma unroll
    for (int mi = 0; mi < NM; mi++)
        #pragma unroll
        for (int nj = 0; nj < NN; nj++) {
            int colg = n0 + wn + nj * 16 + l15;
            int rowb = m0 + wm + mi * 16 + l4 * 4;
            if (Cpart) {
                float* cp = Cpart + (size_t)z * M * N;
                #pragma unroll
                for (int r = 0; r < 4; r++)
                    cp[(size_t)(rowb + r) * N + colg] = acc[mi][nj][r];
                continue;
            }
            float bvv = bias ? bias[colg] : 0.f;
            float vals[4];
            #pragma unroll
            for (int r = 0; r < 4; r++) {
                float v = acc[mi][nj][r] + bvv;
                vals[r] = relu ? fmaxf(v, 0.f) : v;
            }
            if (Cvt && colg >= 256) {
                s4 pk = { (short)f2bf(vals[0]), (short)f2bf(vals[1]),
                          (short)f2bf(vals[2]), (short)f2bf(vals[3]) };
                *(s4*)&Cvt[(size_t)(colg - 256) * 4096 + rowb] = pk;
            } else {
                #pragma unroll
                for (int r = 0; r < 4; r++) {
                    if (Cf) Cf[(size_t)(rowb + r) * ldc + colg] = vals[r];
                    if (Cb) Cb[(size_t)(rowb + r) * ldc + colg] = f2bf(vals[r]);
                }
            }
        }
}

// ------------------------------------------------------------------
// GAT attention-coefficient prep: a_src[n,h], a_dst[n,h]
// ------------------------------------------------------------------
__global__ __launch_bounds__(128) void gat_prep(
    const float* __restrict__ hh, const float* __restrict__ asrc,
    const float* __restrict__ adst, float* __restrict__ an_src,
    float* __restrict__ an_dst)
{
    int n = blockIdx.x, tid = threadIdx.x;
    int head = tid >> 6, c = tid & 63;
    float v = hh[n * 128 + tid];
    float ps = v * asrc[head * 64 + c];
    float pd = v * adst[head * 64 + c];
    for (int off = 32; off; off >>= 1) { ps += __shfl_down(ps, off); pd += __shfl_down(pd, off); }
    if (c == 0) { an_src[n * 2 + head] = ps; an_dst[n * 2 + head] = pd; }
}

// ------------------------------------------------------------------
// CSR build
// ------------------------------------------------------------------
__global__ void count_edges(const int* __restrict__ dst, int* counts, int E) {
    int i = blockIdx.x * 256 + threadIdx.x;
    if (i < E) atomicAdd(&counts[dst[i]], 1);
}

__global__ __launch_bounds__(1024) void scan_kernel(const int* __restrict__ counts,
                                                    int* row_start, int* cursor) {
    __shared__ int s[1024];
    int tid = threadIdx.x, b = tid * 4;
    int c0 = counts[b], c1 = counts[b+1], c2 = counts[b+2], c3 = counts[b+3];
    int sum = c0 + c1 + c2 + c3;
    s[tid] = sum;
    __syncthreads();
    for (int off = 1; off < 1024; off <<= 1) {
        int v = (tid >= off) ? s[tid - off] : 0;
        __syncthreads();
        s[tid] += v;
        __syncthreads();
    }
    int excl = s[tid] - sum;
    int r0 = excl, r1 = excl + c0, r2 = r1 + c1, r3 = r2 + c2;
    row_start[b] = r0; row_start[b+1] = r1; row_start[b+2] = r2; row_start[b+3] = r3;
    cursor[b] = r0; cursor[b+1] = r1; cursor[b+2] = r2; cursor[b+3] = r3;
    if (tid == 1023) row_start[4096] = s[1023];
}

__global__ void scatter_edges(const int* __restrict__ src, const int* __restrict__ dst,
                              int* cursor, int* csr_src, int E) {
    int i = blockIdx.x * 256 + threadIdx.x;
    if (i < E) { int pos = atomicAdd(&cursor[dst[i]], 1); csr_src[pos] = src[i]; }
}

// ------------------------------------------------------------------
// GAT aggregate: one block (256 thr) per destination node.
// Phases 1/2: segment max & denom over all 256 threads.
// Phase 3: 2 edge-groups x 128 channels, LDS combine.
// ------------------------------------------------------------------
__global__ __launch_bounds__(256) void gat_aggregate(
    const int* __restrict__ row_start, const int* __restrict__ csr_src,
    const float* __restrict__ an_src, const float* __restrict__ an_dst,
    const float* __restrict__ hh, const float* __restrict__ gbias,
    float* __restrict__ y32, u16* __restrict__ yb)
{
    int n = blockIdx.x, tid = threadIdx.x;
    const int lane = tid & 63, wv = tid >> 6;
    int start = row_start[n], end = row_start[n + 1];
    float ad0 = an_dst[n * 2 + 0], ad1 = an_dst[n * 2 + 1];
    __shared__ float rmx[4][2], rsm[4][2], sagg[256];

    float mx0 = -1e30f, mx1 = -1e30f;
    for (int i = start + tid; i < end; i += 256) {
        int s = csr_src[i];
        float e0 = an_src[s * 2 + 0] + ad0; e0 = e0 > 0.f ? e0 : 0.2f * e0;
        float e1 = an_src[s * 2 + 1] + ad1; e1 = e1 > 0.f ? e1 : 0.2f * e1;
        mx0 = fmaxf(mx0, e0); mx1 = fmaxf(mx1, e1);
    }
    for (int off = 32; off; off >>= 1) { mx0 = fmaxf(mx0, __shfl_down(mx0, off)); mx1 = fmaxf(mx1, __shfl_down(mx1, off)); }
    if (lane == 0) { rmx[wv][0] = mx0; rmx[wv][1] = mx1; }
    __syncthreads();
    mx0 = fmaxf(fmaxf(rmx[0][0], rmx[1][0]), fmaxf(rmx[2][0], rmx[3][0]));
    mx1 = fmaxf(fmaxf(rmx[0][1], rmx[1][1]), fmaxf(rmx[2][1], rmx[3][1]));

    float s0 = 0.f, s1 = 0.f;
    for (int i = start + tid; i < end; i += 256) {
        int s = csr_src[i];
        float e0 = an_src[s * 2 + 0] + ad0; e0 = e0 > 0.f ? e0 : 0.2f * e0;
        float e1 = an_src[s * 2 + 1] + ad1; e1 = e1 > 0.f ? e1 : 0.2f * e1;
        s0 += __expf(e0 - mx0); s1 += __expf(e1 - mx1);
    }
    for (int off = 32; off; off >>= 1) { s0 += __shfl_down(s0, off); s1 += __shfl_down(s1, off); }
    if (lane == 0) { rsm[wv][0] = s0; rsm[wv][1] = s1; }
    __syncthreads();
    s0 = rsm[0][0] + rsm[1][0] + rsm[2][0] + rsm[3][0];
    s1 = rsm[0][1] + rsm[1][1] + rsm[2][1] + rsm[3][1];

    const int grp = tid >> 7, ch = tid & 127, head = ch >> 6;
    float mx = head ? mx1 : mx0, dn = head ? s1 : s0, ad = head ? ad1 : ad0;
    float agg = 0.f;
    for (int i = start + grp; i < end; i += 2) {
        int s = csr_src[i];
        float e = an_src[s * 2 + head] + ad; e = e > 0.f ? e : 0.2f * e;
        agg += (__expf(e - mx) / dn) * hh[(size_t)s * 128 + ch];
    }
    sagg[tid] = agg;
    __syncthreads();
    if (tid < 128) {
        float v = sagg[tid] + sagg[tid + 128] + gbias[tid];
        y32[(size_t)n * 128 + tid] = v;
        yb[(size_t)n * 128 + tid] = f2bf(v);
    }
}

// ------------------------------------------------------------------
// flash attention partial: grid (N/64, NH, 8). LDS-staged K/V tiles
// (double-buffered, ONE barrier per tile, loads issued post-barrier).
// Swapped QK^T: S^T = mfma(K,Q) -> lane owns q=lane&15; softmax
// in-register + 2 shfl. q pre-scaled by QS (exp2 domain).
// Pitches: K 40, V/P 68 (34 dwords -> 2*l15 bank stride, ~2-way only).
// ------------------------------------------------------------------
__global__ __launch_bounds__(256) void flash_attn_part(
    const u16* __restrict__ q, const u16* __restrict__ k,
    const u16* __restrict__ vt, float* __restrict__ po,
    float* __restrict__ pm, float* __restrict__ pl)
{
    __shared__ __align__(16) u16 Kb[2][64][40];
    __shared__ __align__(16) u16 Vb[2][32][68];
    __shared__ __align__(16) u16 Ps[4][16][68];
    const int q0 = blockIdx.x * 64, h = blockIdx.y, ch = blockIdx.z;
    const int tid = threadIdx.x;
    const int w = tid >> 6, lane = tid & 63, l15 = lane & 15, l4 = lane >> 4;

    bh8 qf = *(const bh8*)&q[(size_t)(q0 + w * 16 + l15) * 256 + h * 32 + l4 * 8];

    const int skey = tid >> 2, sds = (tid & 3) * 8;   // K staging: 64 keys x 32 d
    const int svd = tid >> 3, svk = (tid & 7) * 8;    // V staging: 32 d x 64 keys
    const u16* kgp = &k[(size_t)(ch * 512 + skey) * 256 + h * 32 + sds];
    const u16* vgp = &vt[(size_t)(h * 32 + svd) * 4096 + ch * 512 + svk];

    fx4 o0 = {0,0,0,0}, o1 = {0,0,0,0};
    float M = -1e30f, L = 0.f;

    *(int4*)&Kb[0][skey][sds] = *(const int4*)kgp;
    *(int4*)&Vb[0][svd][svk] = *(const int4*)vgp;

    for (int ti = 0; ti < 8; ti++) {
        const int cur = ti & 1;
        int4 kr, vr;
        __syncthreads();
        if (ti < 7) {   // issue next-tile loads AFTER barrier; compute hides latency
            kr = *(const int4*)(kgp + (size_t)(ti + 1) * 64 * 256);
            vr = *(const int4*)(vgp + (ti + 1) * 64);
        }

        fx4 s[4];
        #pragma unroll
        for (int sub = 0; sub < 4; sub++) {
            bh8 kf = *(const bh8*)&Kb[cur][sub * 16 + l15][l4 * 8];
            fx4 z = {0,0,0,0};
            s[sub] = __builtin_amdgcn_mfma_f32_16x16x32_bf16(kf, qf, z, 0, 0, 0);
        }
        // lane holds S^T[key = sub*16 + l4*4 + r][q = l15]
        float m = fmaxf(fmaxf(s[0][0], s[0][1]), fmaxf(s[0][2], s[0][3]));
        #pragma unroll
        for (int sub = 1; sub < 4; sub++)
            m = fmaxf(m, fmaxf(fmaxf(s[sub][0], s[sub][1]), fmaxf(s[sub][2], s[sub][3])));
        m = fmaxf(m, __shfl_xor(m, 16));
        m = fmaxf(m, __shfl_xor(m, 32));
        float Mn = fmaxf(M, m);
        float f = __builtin_amdgcn_exp2f(M - Mn);
        M = Mn;
        o0 *= f; o1 *= f; L *= f;

        float lsum = 0.f;
        #pragma unroll
        for (int sub = 0; sub < 4; sub++)
            #pragma unroll
            for (int r = 0; r < 4; r++) {
                float pv = __builtin_amdgcn_exp2f(s[sub][r] - M);
                s[sub][r] = pv;
                lsum += pv;
            }
        lsum += __shfl_xor(lsum, 16);
        lsum += __shfl_xor(lsum, 32);
        L += lsum;

        // pack P^T into Ps[w][q][key] (wave-private; DS in-order per wave)
        #pragma unroll
        for (int sub = 0; sub < 4; sub++) {
            u32 w0 = (u32)f2bf(s[sub][0]) | ((u32)f2bf(s[sub][1]) << 16);
            u32 w1 = (u32)f2bf(s[sub][2]) | ((u32)f2bf(s[sub][3]) << 16);
            *(u32*)&Ps[w][l15][sub * 16 + l4 * 4]     = w0;
            *(u32*)&Ps[w][l15][sub * 16 + l4 * 4 + 2] = w1;
        }

        // PV: O^T += V^T @ P^T
        #pragma unroll
        for (int kc = 0; kc < 2; kc++) {
            bh8 bf  = *(const bh8*)&Ps[w][l15][kc * 32 + l4 * 8];
            bh8 af0 = *(const bh8*)&Vb[cur][l15][kc * 32 + l4 * 8];
            bh8 af1 = *(const bh8*)&Vb[cur][16 + l15][kc * 32 + l4 * 8];
            o0 = __builtin_amdgcn_mfma_f32_16x16x32_bf16(af0, bf, o0, 0, 0, 0);
            o1 = __builtin_amdgcn_mfma_f32_16x16x32_bf16(af1, bf, o1, 0, 0, 0);
        }

        if (ti < 7) {   // write next tile (vmcnt waits land here, after compute)
            *(int4*)&Kb[cur ^ 1][skey][sds] = kr;
            *(int4*)&Vb[cur ^ 1][svd][svk] = vr;
        }
    }
    // o0[r] = O^T[d = l4*4+r][q = l15], o1: d+16
    const int base = (blockIdx.x * 4 + h) * 8 + ch;
    const int qrow = w * 16 + l15;
    *(fx4*)&po[(size_t)(base * 64 + qrow) * 32 + l4 * 4]      = o0;
    *(fx4*)&po[(size_t)(base * 64 + qrow) * 32 + 16 + l4 * 4] = o1;
    if (l4 == 0) { pm[base * 64 + qrow] = M; pl[base * 64 + qrow] = L; }
}

// ------------------------------------------------------------------
// combine the 8 KV-chunk partials
// ------------------------------------------------------------------
__global__ __launch_bounds__(256) void attn_combine(
    const float* __restrict__ po, const float* __restrict__ pm,
    const float* __restrict__ pl, u16* __restrict__ out)
{
    int qb = blockIdx.x, h = blockIdx.y;
    int col = threadIdx.x & 31, r0 = threadIdx.x >> 5;
    int rb = (qb * 4 + h) * 8;
    for (int j = 0; j < 8; j++) {
        int row = r0 * 8 + j;
        float m = -1e30f;
        for (int c = 0; c < 8; c++) m = fmaxf(m, pm[(rb + c) * 64 + row]);
        float l = 0.f, o = 0.f;
        for (int c = 0; c < 8; c++) {
            float wgt = __builtin_amdgcn_exp2f(pm[(rb + c) * 64 + row] - m);
            l += wgt * pl[(rb + c) * 64 + row];
            o += wgt * po[(size_t)((rb + c) * 64 + row) * 32 + col];
        }
        out[(size_t)(qb * 64 + row) * 128 + h * 32 + col] = f2bf(o / l);
    }
}

// ------------------------------------------------------------------
// residual add + LayerNorm (128 channels), writes f32 + bf16
// ------------------------------------------------------------------
__global__ __launch_bounds__(128) void add_ln(
    const float* __restrict__ y, const float* __restrict__ delta,
    const float* __restrict__ g, const float* __restrict__ b,
    float* __restrict__ out32, u16* __restrict__ outb)
{
    int n = blockIdx.x, tid = threadIdx.x;
    float v = y[(size_t)n * 128 + tid] + delta[(size_t)n * 128 + tid];
    float sacc = v;
    for (int off = 32; off; off >>= 1) sacc += __shfl_down(sacc, off);
    __shared__ float sm[2], sv[2];
    if ((tid & 63) == 0) sm[tid >> 6] = sacc;
    __syncthreads();
    float mean = (sm[0] + sm[1]) * (1.f / 128.f);
    float d = v - mean;
    float qacc = d * d;
    for (int off = 32; off; off >>= 1) qacc += __shfl_down(qacc, off);
    if ((tid & 63) == 0) sv[tid >> 6] = qacc;
    __syncthreads();
    float var = (sv[0] + sv[1]) * (1.f / 128.f);
    float o = d * rsqrtf(var + 1e-5f) * g[tid] + b[tid];
    out32[(size_t)n * 128 + tid] = o;
    outb[(size_t)n * 128 + tid] = f2bf(o);
}

// ------------------------------------------------------------------
// residual add + sum of 8 split-K partials + bias + LayerNorm
// ------------------------------------------------------------------
__global__ __launch_bounds__(128) void add_ln8(
    const float* __restrict__ y, const float* __restrict__ part,
    const float* __restrict__ bias,
    const float* __restrict__ g, const float* __restrict__ b,
    float* __restrict__ out32, u16* __restrict__ outb)
{
    int n = blockIdx.x, tid = threadIdx.x;
    float v = y[(size_t)n * 128 + tid] + bias[tid];
    for (int z = 0; z < 8; z++) v += part[(size_t)z * 524288 + n * 128 + tid];
    float sacc = v;
    for (int off = 32; off; off >>= 1) sacc += __shfl_down(sacc, off);
    __shared__ float sm[2], sv[2];
    if ((tid & 63) == 0) sm[tid >> 6] = sacc;
    __syncthreads();
    float mean = (sm[0] + sm[1]) * (1.f / 128.f);
    float d = v - mean;
    float qacc = d * d;
    for (int off = 32; off; off >>= 1) qacc += __shfl_down(qacc, off);
    if ((tid & 63) == 0) sv[tid >> 6] = qacc;
    __syncthreads();
    float var = (sv[0] + sv[1]) * (1.f / 128.f);
    float o = d * rsqrtf(var + 1e-5f) * g[tid] + b[tid];
    out32[(size_t)n * 128 + tid] = o;
    outb[(size_t)n * 128 + tid] = f2bf(o);
}

// ------------------------------------------------------------------
extern "C" void kernel_launch(void* const* d_in, const int* in_sizes, int n_in,
                              void* d_out, int out_size, void* d_ws, size_t ws_size,
                              hipStream_t stream)
{
    const float* x     = (const float*)d_in[0];
    const int*   ei    = (const int*)  d_in[1];
    const float* ew1   = (const float*)d_in[2];
    const float* eb1   = (const float*)d_in[3];
    const float* ew2   = (const float*)d_in[4];
    const float* eb2   = (const float*)d_in[5];
    const float* gw    = (const float*)d_in[6];
    const float* gasrc = (const float*)d_in[7];
    const float* gadst = (const float*)d_in[8];
    const float* gbias = (const float*)d_in[9];
    const float* wq    = (const float*)d_in[10];
    const float* bq    = (const float*)d_in[11];
    const float* wk    = (const float*)d_in[12];
    const float* bk    = (const float*)d_in[13];
    const float* wv    = (const float*)d_in[14];
    const float* bv    = (const float*)d_in[15];
    const float* wo    = (const float*)d_in[16];
    const float* bo    = (const float*)d_in[17];
    const float* ln1g  = (const float*)d_in[18];
    const float* ln1b  = (const float*)d_in[19];
    const float* ln2g  = (const float*)d_in[20];
    const float* ln2b  = (const float*)d_in[21];
    const float* w1    = (const float*)d_in[22];
    const float* b1    = (const float*)d_in[23];
    const float* w2    = (const float*)d_in[24];
    const float* b2    = (const float*)d_in[25];

    const int E = in_sizes[1] / 2;
    const int* esrc = ei;
    const int* edst = ei + E;

    char* p = (char*)d_ws;
    auto alloc = [&](size_t bytes) -> void* {
        void* r = (void*)p;
        p += (bytes + 255) & ~(size_t)255;
        return r;
    };
    u16* xb    = (u16*)alloc(4096 * 256 * 2);
    u16* ew1t  = (u16*)alloc(128 * 256 * 2);
    u16* ew2t  = (u16*)alloc(128 * 128 * 2);
    u16* gwt   = (u16*)alloc(128 * 128 * 2);
    u16* wqkvt = (u16*)alloc(2 * 384 * 128 * 2);
    float* bqkv = (float*)alloc(2 * 384 * 4);
    u16* wot   = (u16*)alloc(2 * 128 * 128 * 2);
    u16* w1t   = (u16*)alloc(2 * 2048 * 128 * 2);
    u16* w2t   = (u16*)alloc(2 * 128 * 2048 * 2);
    u16* h1b   = (u16*)alloc(4096 * 128 * 2);
    u16* hb    = (u16*)alloc(4096 * 128 * 2);
    float* hh  = (float*)alloc(4096 * 128 * 4);
    float* ansrc = (float*)alloc(4096 * 2 * 4);
    float* andst = (float*)alloc(4096 * 2 * 4);
    int* counts    = (int*)alloc(4096 * 4);
    int* row_start = (int*)alloc(4097 * 4);
    int* cursor    = (int*)alloc(4096 * 4);
    int* csr_src   = (int*)alloc((size_t)E * 4);
    float* y32 = (float*)alloc(4096 * 128 * 4);
    u16* yb    = (u16*)alloc(4096 * 128 * 2);
    u16* qkvb  = (u16*)alloc((size_t)4096 * 256 * 2);   // Q,K only (pitch 256)
    u16* vtb   = (u16*)alloc(4096 * 128 * 2);           // V transposed [128][4096]
    u16* attnb = (u16*)alloc(4096 * 128 * 2);
    float* po  = (float*)alloc((size_t)64 * 4 * 8 * 64 * 32 * 4);
    float* pm  = (float*)alloc(64 * 4 * 8 * 64 * 4);
    float* pl  = (float*)alloc(64 * 4 * 8 * 64 * 4);
    float* proj32 = (float*)alloc(4096 * 128 * 4);
    u16* ff1b  = (u16*)alloc((size_t)4096 * 2048 * 2);
    float* ff2part = (float*)alloc((size_t)8 * 4096 * 128 * 4);

    // ---- prep ----
    prep_kernel<<<433, 256, 0, stream>>>(x, ew1, ew2, gw, wq, wk, wv, wo, w1, w2,
                                         bq, bk, bv,
                                         xb, ew1t, ew2t, gwt, wqkvt, bqkv, wot, w1t, w2t);

    // ---- encoder MLP ----
    gemm_t<32, 64><<<dim3(128, 2), 256, 0, stream>>>(xb, ew1t, eb1, nullptr, h1b, nullptr, nullptr, 4096, 128, 256, 1, 256, 128);
    gemm_t<32, 64><<<dim3(128, 2), 256, 0, stream>>>(h1b, ew2t, eb2, nullptr, hb, nullptr, nullptr, 4096, 128, 128, 0, 128, 128);

    // ---- GAT ----
    gemm_t<32, 64><<<dim3(128, 2), 256, 0, stream>>>(hb, gwt, nullptr, hh, nullptr, nullptr, nullptr, 4096, 128, 128, 0, 128, 128);
    gat_prep<<<4096, 128, 0, stream>>>(hh, gasrc, gadst, ansrc, andst);
    hipMemsetAsync(counts, 0, 4096 * sizeof(int), stream);
    count_edges<<<(E + 255) / 256, 256, 0, stream>>>(edst, counts, E);
    scan_kernel<<<1, 1024, 0, stream>>>(counts, row_start, cursor);
    scatter_edges<<<(E + 255) / 256, 256, 0, stream>>>(esrc, edst, cursor, csr_src, E);
    gat_aggregate<<<4096, 256, 0, stream>>>(row_start, csr_src, ansrc, andst, hh, gbias, y32, yb);

    // ---- transformer layers ----
    for (int l = 0; l < 2; l++) {
        gemm_t<64, 64><<<dim3(64, 6), 256, 0, stream>>>(yb, wqkvt + l * 49152, bqkv + l * 384, nullptr, qkvb, nullptr, vtb, 4096, 384, 128, 0, 128, 256);
        flash_attn_part<<<dim3(64, 4, 8), 256, 0, stream>>>(qkvb, qkvb + 128, vtb, po, pm, pl);
        attn_combine<<<dim3(64, 4), 256, 0, stream>>>(po, pm, pl, attnb);
        gemm_t<32, 64><<<dim3(128, 2), 256, 0, stream>>>(attnb, wot + l * 16384, bo + l * 128, proj32, nullptr, nullptr, nullptr, 4096, 128, 128, 0, 128, 128);
        add_ln<<<4096, 128, 0, stream>>>(y32, proj32, ln1g + l * 128, ln1b + l * 128, y32, yb);
        gemm_t<128, 128><<<dim3(32, 16), 256, 0, stream>>>(yb, w1t + (size_t)l * 262144, b1 + l * 2048, nullptr, ff1b, nullptr, nullptr, 4096, 2048, 128, 1, 128, 2048);
        gemm_t<128, 128><<<dim3(32, 1, 8), 256, 0, stream>>>(ff1b, w2t + (size_t)l * 262144, nullptr, nullptr, nullptr, ff2part, nullptr, 4096, 128, 2048, 0, 256, 128);
        float* outp = (l == 1) ? (float*)d_out : y32;
        add_ln8<<<4096, 128, 0, stream>>>(y32, ff2part, b2 + l * 128, ln2g + l * 128, ln2b + l * 128, outp, yb);
    }
}

// Round 6
// 209.801 us; speedup vs baseline: 1.2395x; 1.2395x over previous
//
#include <hip/hip_runtime.h>

typedef unsigned short u16;
typedef unsigned int u32;
typedef __attribute__((ext_vector_type(8))) short bh8;   // 8 x bf16 raw bits
typedef __attribute__((ext_vector_type(4))) float fx4;
typedef __attribute__((ext_vector_type(4))) short s4;
typedef __attribute__((ext_vector_type(2))) unsigned int u32x2;

#define QS 0.2550437194342803f   /* (1/sqrt(32)) * log2(e) */

__device__ __forceinline__ u16 f2bf(float f) {
    unsigned u = __float_as_uint(f);
    u += 0x7fffu + ((u >> 16) & 1u);   // round-to-nearest-even
    return (u16)(u >> 16);
}

__device__ __forceinline__ u32 cvtpk(float lo, float hi) {
    u32 r;
    asm("v_cvt_pk_bf16_f32 %0, %1, %2" : "=v"(r) : "v"(lo), "v"(hi));
    return r;
}

// ------------------------------------------------------------------
// prep: x -> bf16 (vectorized copy); all weights transposed via tiled
// 64x64 LDS transpose (coalesced global reads AND writes); fused QKV
// weight/bias with Q side pre-scaled by QS (softmax in exp2 domain).
// grid = 128 (x) + 1 (bias) + 304 transpose tiles = 433 blocks
// ------------------------------------------------------------------
__global__ __launch_bounds__(256) void prep_kernel(
    const float* x, const float* ew1, const float* ew2, const float* gw,
    const float* wq, const float* wk, const float* wv, const float* wo,
    const float* w1, const float* w2,
    const float* bq, const float* bk, const float* bv,
    u16* xb, u16* ew1t, u16* ew2t, u16* gwt,
    u16* wqkvt, float* bqkv, u16* wot, u16* w1t, u16* w2t)
{
    __shared__ u16 tile[64 * 65];
    int bid = blockIdx.x;
    const int t = threadIdx.x;

    if (bid < 128) {   // x convert: 1M floats
        const float4* x4 = (const float4*)x;
        s4* o4 = (s4*)xb;
        #pragma unroll
        for (int i = 0; i < 8; i++) {
            int fi = bid * 2048 + i * 256 + t;
            float4 v = x4[fi];
            s4 o = { (short)f2bf(v.x), (short)f2bf(v.y), (short)f2bf(v.z), (short)f2bf(v.w) };
            o4[fi] = o;
        }
        return;
    }
    bid -= 128;
    if (bid < 1) {     // bqkv [2][384]
        for (int idx = t; idx < 768; idx += 256) {
            int l = idx / 384, n = idx % 384;
            float v;
            if (n < 128)      v = bq[l * 128 + n] * QS;
            else if (n < 256) v = bk[l * 128 + n - 128];
            else              v = bv[l * 128 + n - 256];
            bqkv[idx] = v;
        }
        return;
    }
    bid -= 1;

    const float* src; u16* dst; int R, C, tr, tc; float sc = 1.f;
    if (bid < 8)            { src = ew1; dst = ew1t; R = 256; C = 128; tr = bid >> 1; tc = bid & 1; }
    else if ((bid -= 8) < 4)  { src = ew2; dst = ew2t; R = 128; C = 128; tr = bid >> 1; tc = bid & 1; }
    else if ((bid -= 4) < 4)  { src = gw;  dst = gwt;  R = 128; C = 128; tr = bid >> 1; tc = bid & 1; }
    else if ((bid -= 4) < 24) {
        int l = bid / 12, r2 = bid % 12, which = r2 >> 2, i = r2 & 3;
        R = 128; C = 128; tr = i >> 1; tc = i & 1;
        if (which == 0)      { src = wq + l * 16384; dst = wqkvt + l * 49152;         sc = QS; }
        else if (which == 1) { src = wk + l * 16384; dst = wqkvt + l * 49152 + 16384; }
        else                 { src = wv + l * 16384; dst = wqkvt + l * 49152 + 32768; }
    }
    else if ((bid -= 24) < 8)   { int l = bid >> 2, i = bid & 3;  src = wo + l * 16384; dst = wot + l * 16384; R = 128; C = 128; tr = i >> 1; tc = i & 1; }
    else if ((bid -= 8) < 128)  { int l = bid >> 6, i = bid & 63; src = w1 + (size_t)l * 262144; dst = w1t + (size_t)l * 262144; R = 128;  C = 2048; tr = i & 1;  tc = i >> 1; }
    else { bid -= 128;            int l = bid >> 6, i = bid & 63; src = w2 + (size_t)l * 262144; dst = w2t + (size_t)l * 262144; R = 2048; C = 128;  tr = i >> 1; tc = i & 1; }

    // transpose 64x64 tile: dst[(tc*64+c)*R + tr*64 + r] = src[(tr*64+r)*C + tc*64 + c]
    const int r = t >> 2, cs = (t & 3) * 16;
    const float* sp = src + (size_t)(tr * 64 + r) * C + tc * 64 + cs;
    #pragma unroll
    for (int j = 0; j < 16; j++) tile[r * 65 + cs + j] = f2bf(sp[j] * sc);
    __syncthreads();
    u16* dp = dst + (size_t)(tc * 64 + r) * R + tr * 64 + cs;
    #pragma unroll
    for (int j = 0; j < 16; j++) dp[j] = tile[(cs + j) * 65 + r];
}

// ------------------------------------------------------------------
// staged bf16 MFMA GEMM: C[M,N] = A[M,K] @ Bt[N,K]^T (+bias, relu)
// 64x64 tile, 4 waves each 32x32. Double-buffered LDS, ONE barrier per
// K-step: loads for step t+1 issue right after the barrier, compute
// covers latency, ds_write at end. split-K -> f32 partial to Cpart.
// Cvt: cols >=256 written transposed (V of the QKV GEMM).
// ------------------------------------------------------------------
__global__ __launch_bounds__(256) void gemm_bf16(
    const u16* __restrict__ A, const u16* __restrict__ Bt,
    const float* __restrict__ bias,
    float* __restrict__ Cf, u16* __restrict__ Cb, float* __restrict__ Cpart,
    u16* __restrict__ Cvt,
    int M, int N, int K, int relu, int kchunk, int ldc)
{
    __shared__ __align__(16) u16 As[2][64][40];
    __shared__ __align__(16) u16 Bs[2][64][40];
    const int m0 = blockIdx.x * 64, n0 = blockIdx.y * 64, z = blockIdx.z;
    const int tid = threadIdx.x;
    const int lane = tid & 63, w = tid >> 6;
    const int wm = (w >> 1) * 32, wn = (w & 1) * 32;
    const int l15 = lane & 15, l4 = lane >> 4;
    const int srow = tid >> 2, skq = (tid & 3) * 8;
    const int k0 = z * kchunk;

    const u16* Ap = A + (size_t)(m0 + srow) * K + k0 + skq;
    const u16* Bp = Bt + (size_t)(n0 + srow) * K + k0 + skq;

    fx4 acc00 = {0,0,0,0}, acc01 = {0,0,0,0}, acc10 = {0,0,0,0}, acc11 = {0,0,0,0};

    *(int4*)&As[0][srow][skq] = *(const int4*)Ap;
    *(int4*)&Bs[0][srow][skq] = *(const int4*)Bp;

    const int niter = kchunk >> 5;
    for (int it = 0; it < niter; it++) {
        const int cur = it & 1;
        int4 ar, br;
        __syncthreads();
        if (it + 1 < niter) {
            ar = *(const int4*)(Ap + (it + 1) * 32);
            br = *(const int4*)(Bp + (it + 1) * 32);
        }
        bh8 a0 = *(const bh8*)&As[cur][wm + l15][l4 * 8];
        bh8 a1 = *(const bh8*)&As[cur][wm + 16 + l15][l4 * 8];
        bh8 b0 = *(const bh8*)&Bs[cur][wn + l15][l4 * 8];
        bh8 b1 = *(const bh8*)&Bs[cur][wn + 16 + l15][l4 * 8];
        acc00 = __builtin_amdgcn_mfma_f32_16x16x32_bf16(a0, b0, acc00, 0, 0, 0);
        acc01 = __builtin_amdgcn_mfma_f32_16x16x32_bf16(a0, b1, acc01, 0, 0, 0);
        acc10 = __builtin_amdgcn_mfma_f32_16x16x32_bf16(a1, b0, acc10, 0, 0, 0);
        acc11 = __builtin_amdgcn_mfma_f32_16x16x32_bf16(a1, b1, acc11, 0, 0, 0);
        if (it + 1 < niter) {
            *(int4*)&As[cur ^ 1][srow][skq] = ar;
            *(int4*)&Bs[cur ^ 1][srow][skq] = br;
        }
    }

    fx4* accs[2][2] = {{&acc00, &acc01}, {&acc10, &acc11}};
    #pragma unroll
    for (int i = 0; i < 2; i++)
        #pragma unroll
        for (int j = 0; j < 2; j++) {
            int colg = n0 + wn + j * 16 + l15;
            int rowb = m0 + wm + i * 16 + l4 * 4;
            if (Cpart) {
                float* cp = Cpart + (size_t)z * M * N;
                #pragma unroll
                for (int r = 0; r < 4; r++)
                    cp[(size_t)(rowb + r) * N + colg] = (*accs[i][j])[r];
                continue;
            }
            float bvv = bias ? bias[colg] : 0.f;
            float vals[4];
            #pragma unroll
            for (int r = 0; r < 4; r++) {
                float v = (*accs[i][j])[r] + bvv;
                vals[r] = relu ? fmaxf(v, 0.f) : v;
            }
            if (Cvt && colg >= 256) {
                s4 pk = { (short)f2bf(vals[0]), (short)f2bf(vals[1]),
                          (short)f2bf(vals[2]), (short)f2bf(vals[3]) };
                *(s4*)&Cvt[(size_t)(colg - 256) * 4096 + rowb] = pk;
            } else {
                #pragma unroll
                for (int r = 0; r < 4; r++) {
                    if (Cf) Cf[(size_t)(rowb + r) * ldc + colg] = vals[r];
                    if (Cb) Cb[(size_t)(rowb + r) * ldc + colg] = f2bf(vals[r]);
                }
            }
        }
}

// ------------------------------------------------------------------
// GAT attention-coefficient prep: a_src[n,h], a_dst[n,h]
// ------------------------------------------------------------------
__global__ __launch_bounds__(128) void gat_prep(
    const float* __restrict__ hh, const float* __restrict__ asrc,
    const float* __restrict__ adst, float* __restrict__ an_src,
    float* __restrict__ an_dst)
{
    int n = blockIdx.x, tid = threadIdx.x;
    int head = tid >> 6, c = tid & 63;
    float v = hh[n * 128 + tid];
    float ps = v * asrc[head * 64 + c];
    float pd = v * adst[head * 64 + c];
    for (int off = 32; off; off >>= 1) { ps += __shfl_down(ps, off); pd += __shfl_down(pd, off); }
    if (c == 0) { an_src[n * 2 + head] = ps; an_dst[n * 2 + head] = pd; }
}

// ------------------------------------------------------------------
// CSR build
// ------------------------------------------------------------------
__global__ void count_edges(const int* __restrict__ dst, int* counts, int E) {
    int i = blockIdx.x * 256 + threadIdx.x;
    if (i < E) atomicAdd(&counts[dst[i]], 1);
}

__global__ __launch_bounds__(1024) void scan_kernel(const int* __restrict__ counts,
                                                    int* row_start, int* cursor) {
    __shared__ int s[1024];
    int tid = threadIdx.x, b = tid * 4;
    int c0 = counts[b], c1 = counts[b+1], c2 = counts[b+2], c3 = counts[b+3];
    int sum = c0 + c1 + c2 + c3;
    s[tid] = sum;
    __syncthreads();
    for (int off = 1; off < 1024; off <<= 1) {
        int v = (tid >= off) ? s[tid - off] : 0;
        __syncthreads();
        s[tid] += v;
        __syncthreads();
    }
    int excl = s[tid] - sum;
    int r0 = excl, r1 = excl + c0, r2 = r1 + c1, r3 = r2 + c2;
    row_start[b] = r0; row_start[b+1] = r1; row_start[b+2] = r2; row_start[b+3] = r3;
    cursor[b] = r0; cursor[b+1] = r1; cursor[b+2] = r2; cursor[b+3] = r3;
    if (tid == 1023) row_start[4096] = s[1023];
}

__global__ void scatter_edges(const int* __restrict__ src, const int* __restrict__ dst,
                              int* cursor, int* csr_src, int E) {
    int i = blockIdx.x * 256 + threadIdx.x;
    if (i < E) { int pos = atomicAdd(&cursor[dst[i]], 1); csr_src[pos] = src[i]; }
}

// ------------------------------------------------------------------
// GAT aggregate: one block (256 thr) per destination node.
// Pass 1/2: segment max & denom. Pass 3: chunked — 128 threads compute
// alpha (exp once per edge, pre-divided) into LDS, then 2 edge-groups
// x 128 channels accumulate pure fma; LDS combine at end.
// ------------------------------------------------------------------
__global__ __launch_bounds__(256) void gat_aggregate(
    const int* __restrict__ row_start, const int* __restrict__ csr_src,
    const float* __restrict__ an_src, const float* __restrict__ an_dst,
    const float* __restrict__ hh, const float* __restrict__ gbias,
    float* __restrict__ y32, u16* __restrict__ yb)
{
    int n = blockIdx.x, tid = threadIdx.x;
    const int lane = tid & 63, wv = tid >> 6;
    int start = row_start[n], end = row_start[n + 1];
    float ad0 = an_dst[n * 2 + 0], ad1 = an_dst[n * 2 + 1];
    __shared__ float rmx[4][2], rsm[4][2];
    __shared__ float sal0[128], sal1[128], sagg[256];
    __shared__ int sidx[128];

    float mx0 = -1e30f, mx1 = -1e30f;
    for (int i = start + tid; i < end; i += 256) {
        int s = csr_src[i];
        float e0 = an_src[s * 2 + 0] + ad0; e0 = e0 > 0.f ? e0 : 0.2f * e0;
        float e1 = an_src[s * 2 + 1] + ad1; e1 = e1 > 0.f ? e1 : 0.2f * e1;
        mx0 = fmaxf(mx0, e0); mx1 = fmaxf(mx1, e1);
    }
    for (int off = 32; off; off >>= 1) { mx0 = fmaxf(mx0, __shfl_down(mx0, off)); mx1 = fmaxf(mx1, __shfl_down(mx1, off)); }
    if (lane == 0) { rmx[wv][0] = mx0; rmx[wv][1] = mx1; }
    __syncthreads();
    mx0 = fmaxf(fmaxf(rmx[0][0], rmx[1][0]), fmaxf(rmx[2][0], rmx[3][0]));
    mx1 = fmaxf(fmaxf(rmx[0][1], rmx[1][1]), fmaxf(rmx[2][1], rmx[3][1]));

    float den0 = 0.f, den1 = 0.f;
    for (int i = start + tid; i < end; i += 256) {
        int s = csr_src[i];
        float e0 = an_src[s * 2 + 0] + ad0; e0 = e0 > 0.f ? e0 : 0.2f * e0;
        float e1 = an_src[s * 2 + 1] + ad1; e1 = e1 > 0.f ? e1 : 0.2f * e1;
        den0 += __expf(e0 - mx0); den1 += __expf(e1 - mx1);
    }
    for (int off = 32; off; off >>= 1) { den0 += __shfl_down(den0, off); den1 += __shfl_down(den1, off); }
    if (lane == 0) { rsm[wv][0] = den0; rsm[wv][1] = den1; }
    __syncthreads();
    den0 = rsm[0][0] + rsm[1][0] + rsm[2][0] + rsm[3][0];
    den1 = rsm[0][1] + rsm[1][1] + rsm[2][1] + rsm[3][1];
    float rd0 = 1.f / den0, rd1 = 1.f / den1;

    const int grp = tid >> 7, ch = tid & 127, head = ch >> 6;
    float agg = 0.f;
    for (int c0 = start; c0 < end; c0 += 128) {
        int cnt = min(128, end - c0);
        __syncthreads();
        if (tid < cnt) {
            int s = csr_src[c0 + tid];
            float e0 = an_src[s * 2 + 0] + ad0; e0 = e0 > 0.f ? e0 : 0.2f * e0;
            float e1 = an_src[s * 2 + 1] + ad1; e1 = e1 > 0.f ? e1 : 0.2f * e1;
            sal0[tid] = __expf(e0 - mx0) * rd0;
            sal1[tid] = __expf(e1 - mx1) * rd1;
            sidx[tid] = s;
        }
        __syncthreads();
        const float* sal = head ? sal1 : sal0;
        for (int j = grp; j < cnt; j += 2)
            agg += sal[j] * hh[(size_t)sidx[j] * 128 + ch];
    }
    sagg[tid] = agg;
    __syncthreads();
    if (tid < 128) {
        float v = sagg[tid] + sagg[tid + 128] + gbias[tid];
        y32[(size_t)n * 128 + tid] = v;
        yb[(size_t)n * 128 + tid] = f2bf(v);
    }
}

// ------------------------------------------------------------------
// flash attention partial: grid (N/64, NH, 8). LDS-staged K/V tiles
// (double-buffered, ONE barrier per tile, loads issued post-barrier).
// Swapped QK^T: S^T = mfma(K,Q) -> lane owns q=lane&15; softmax
// in-register: max3 tree + 2 shfl, defer-max (THR=8, exp2 domain),
// cvt_pk bf16 pack, b64 P writes. q pre-scaled by QS.
// ------------------------------------------------------------------
__global__ __launch_bounds__(256) void flash_attn_part(
    const u16* __restrict__ q, const u16* __restrict__ k,
    const u16* __restrict__ vt, float* __restrict__ po,
    float* __restrict__ pm, float* __restrict__ pl)
{
    __shared__ __align__(16) u16 Kb[2][64][40];
    __shared__ __align__(16) u16 Vb[2][32][72];
    __shared__ __align__(16) u16 Ps[4][16][72];
    const int q0 = blockIdx.x * 64, h = blockIdx.y, ch = blockIdx.z;
    const int tid = threadIdx.x;
    const int w = tid >> 6, lane = tid & 63, l15 = lane & 15, l4 = lane >> 4;

    bh8 qf = *(const bh8*)&q[(size_t)(q0 + w * 16 + l15) * 256 + h * 32 + l4 * 8];

    const int skey = tid >> 2, sds = (tid & 3) * 8;   // K staging: 64 keys x 32 d
    const int svd = tid >> 3, svk = (tid & 7) * 8;    // V staging: 32 d x 64 keys
    const u16* kgp = &k[(size_t)(ch * 512 + skey) * 256 + h * 32 + sds];
    const u16* vgp = &vt[(size_t)(h * 32 + svd) * 4096 + ch * 512 + svk];

    fx4 o0 = {0,0,0,0}, o1 = {0,0,0,0};
    float M = -1e30f, L = 0.f;

    *(int4*)&Kb[0][skey][sds] = *(const int4*)kgp;
    *(int4*)&Vb[0][svd][svk] = *(const int4*)vgp;

    for (int ti = 0; ti < 8; ti++) {
        const int cur = ti & 1;
        int4 kr, vr;
        __syncthreads();
        if (ti < 7) {   // issue next-tile loads AFTER barrier; compute hides latency
            kr = *(const int4*)(kgp + (size_t)(ti + 1) * 64 * 256);
            vr = *(const int4*)(vgp + (ti + 1) * 64);
        }

        fx4 s[4];
        #pragma unroll
        for (int sub = 0; sub < 4; sub++) {
            bh8 kf = *(const bh8*)&Kb[cur][sub * 16 + l15][l4 * 8];
            fx4 z = {0,0,0,0};
            s[sub] = __builtin_amdgcn_mfma_f32_16x16x32_bf16(kf, qf, z, 0, 0, 0);
        }
        // lane holds S^T[key = sub*16 + l4*4 + r][q = l15]
        // max tree in max3-friendly groups (15 -> ~8 instrs)
        float t0 = fmaxf(fmaxf(s[0][0], s[0][1]), s[0][2]);
        float t1 = fmaxf(fmaxf(s[0][3], s[1][0]), s[1][1]);
        float t2 = fmaxf(fmaxf(s[1][2], s[1][3]), s[2][0]);
        float t3 = fmaxf(fmaxf(s[2][1], s[2][2]), s[2][3]);
        float t4 = fmaxf(fmaxf(s[3][0], s[3][1]), s[3][2]);
        float pmax = fmaxf(fmaxf(fmaxf(t0, t1), t2), fmaxf(fmaxf(t3, t4), s[3][3]));
        pmax = fmaxf(pmax, __shfl_xor(pmax, 16));
        pmax = fmaxf(pmax, __shfl_xor(pmax, 32));
        // defer-max: only rescale when the running max grew by > 8
        if (!__all(pmax - M <= 8.0f)) {
            float f = __builtin_amdgcn_exp2f(M - pmax);
            M = pmax;
            o0 *= f; o1 *= f; L *= f;
        }

        #pragma unroll
        for (int sub = 0; sub < 4; sub++)
            #pragma unroll
            for (int r = 0; r < 4; r++)
                s[sub][r] = __builtin_amdgcn_exp2f(s[sub][r] - M);
        // pairwise tree sum
        float ss0 = (s[0][0] + s[0][1]) + (s[0][2] + s[0][3]);
        float ss1 = (s[1][0] + s[1][1]) + (s[1][2] + s[1][3]);
        float ss2 = (s[2][0] + s[2][1]) + (s[2][2] + s[2][3]);
        float ss3 = (s[3][0] + s[3][1]) + (s[3][2] + s[3][3]);
        float lsum = (ss0 + ss1) + (ss2 + ss3);
        lsum += __shfl_xor(lsum, 16);
        lsum += __shfl_xor(lsum, 32);
        L += lsum;

        // pack P^T into Ps[w][q][key] (wave-private; DS in-order per wave)
        #pragma unroll
        for (int sub = 0; sub < 4; sub++) {
            u32x2 pk = { cvtpk(s[sub][0], s[sub][1]), cvtpk(s[sub][2], s[sub][3]) };
            *(u32x2*)&Ps[w][l15][sub * 16 + l4 * 4] = pk;
        }

        // PV: O^T += V^T @ P^T
        #pragma unroll
        for (int kc = 0; kc < 2; kc++) {
            bh8 bf  = *(const bh8*)&Ps[w][l15][kc * 32 + l4 * 8];
            bh8 af0 = *(const bh8*)&Vb[cur][l15][kc * 32 + l4 * 8];
            bh8 af1 = *(const bh8*)&Vb[cur][16 + l15][kc * 32 + l4 * 8];
            o0 = __builtin_amdgcn_mfma_f32_16x16x32_bf16(af0, bf, o0, 0, 0, 0);
            o1 = __builtin_amdgcn_mfma_f32_16x16x32_bf16(af1, bf, o1, 0, 0, 0);
        }

        if (ti < 7) {   // write next tile (vmcnt waits land here, after compute)
            *(int4*)&Kb[cur ^ 1][skey][sds] = kr;
            *(int4*)&Vb[cur ^ 1][svd][svk] = vr;
        }
    }
    // o0[r] = O^T[d = l4*4+r][q = l15], o1: d+16
    const int base = (blockIdx.x * 4 + h) * 8 + ch;
    const int qrow = w * 16 + l15;
    *(fx4*)&po[(size_t)(base * 64 + qrow) * 32 + l4 * 4]      = o0;
    *(fx4*)&po[(size_t)(base * 64 + qrow) * 32 + 16 + l4 * 4] = o1;
    if (l4 == 0) { pm[base * 64 + qrow] = M; pl[base * 64 + qrow] = L; }
}

// ------------------------------------------------------------------
// combine the 8 KV-chunk partials
// ------------------------------------------------------------------
__global__ __launch_bounds__(256) void attn_combine(
    const float* __restrict__ po, const float* __restrict__ pm,
    const float* __restrict__ pl, u16* __restrict__ out)
{
    int qb = blockIdx.x, h = blockIdx.y;
    int col = threadIdx.x & 31, r0 = threadIdx.x >> 5;
    int rb = (qb * 4 + h) * 8;
    for (int j = 0; j < 8; j++) {
        int row = r0 * 8 + j;
        float m = -1e30f;
        for (int c = 0; c < 8; c++) m = fmaxf(m, pm[(rb + c) * 64 + row]);
        float l = 0.f, o = 0.f;
        for (int c = 0; c < 8; c++) {
            float wgt = __builtin_amdgcn_exp2f(pm[(rb + c) * 64 + row] - m);
            l += wgt * pl[(rb + c) * 64 + row];
            o += wgt * po[(size_t)((rb + c) * 64 + row) * 32 + col];
        }
        out[(size_t)(qb * 64 + row) * 128 + h * 32 + col] = f2bf(o / l);
    }
}

// ------------------------------------------------------------------
// residual add + LayerNorm (128 channels), writes f32 + bf16
// ------------------------------------------------------------------
__global__ __launch_bounds__(128) void add_ln(
    const float* __restrict__ y, const float* __restrict__ delta,
    const float* __restrict__ g, const float* __restrict__ b,
    float* __restrict__ out32, u16* __restrict__ outb)
{
    int n = blockIdx.x, tid = threadIdx.x;
    float v = y[(size_t)n * 128 + tid] + delta[(size_t)n * 128 + tid];
    float sacc = v;
    for (int off = 32; off; off >>= 1) sacc += __shfl_down(sacc, off);
    __shared__ float sm[2], sv[2];
    if ((tid & 63) == 0) sm[tid >> 6] = sacc;
    __syncthreads();
    float mean = (sm[0] + sm[1]) * (1.f / 128.f);
    float d = v - mean;
    float qacc = d * d;
    for (int off = 32; off; off >>= 1) qacc += __shfl_down(qacc, off);
    if ((tid & 63) == 0) sv[tid >> 6] = qacc;
    __syncthreads();
    float var = (sv[0] + sv[1]) * (1.f / 128.f);
    float o = d * rsqrtf(var + 1e-5f) * g[tid] + b[tid];
    out32[(size_t)n * 128 + tid] = o;
    outb[(size_t)n * 128 + tid] = f2bf(o);
}

// ------------------------------------------------------------------
// residual add + sum of 8 split-K partials + bias + LayerNorm
// ------------------------------------------------------------------
__global__ __launch_bounds__(128) void add_ln8(
    const float* __restrict__ y, const float* __restrict__ part,
    const float* __restrict__ bias,
    const float* __restrict__ g, const float* __restrict__ b,
    float* __restrict__ out32, u16* __restrict__ outb)
{
    int n = blockIdx.x, tid = threadIdx.x;
    float v = y[(size_t)n * 128 + tid] + bias[tid];
    for (int z = 0; z < 8; z++) v += part[(size_t)z * 524288 + n * 128 + tid];
    float sacc = v;
    for (int off = 32; off; off >>= 1) sacc += __shfl_down(sacc, off);
    __shared__ float sm[2], sv[2];
    if ((tid & 63) == 0) sm[tid >> 6] = sacc;
    __syncthreads();
    float mean = (sm[0] + sm[1]) * (1.f / 128.f);
    float d = v - mean;
    float qacc = d * d;
    for (int off = 32; off; off >>= 1) qacc += __shfl_down(qacc, off);
    if ((tid & 63) == 0) sv[tid >> 6] = qacc;
    __syncthreads();
    float var = (sv[0] + sv[1]) * (1.f / 128.f);
    float o = d * rsqrtf(var + 1e-5f) * g[tid] + b[tid];
    out32[(size_t)n * 128 + tid] = o;
    outb[(size_t)n * 128 + tid] = f2bf(o);
}

// ------------------------------------------------------------------
extern "C" void kernel_launch(void* const* d_in, const int* in_sizes, int n_in,
                              void* d_out, int out_size, void* d_ws, size_t ws_size,
                              hipStream_t stream)
{
    const float* x     = (const float*)d_in[0];
    const int*   ei    = (const int*)  d_in[1];
    const float* ew1   = (const float*)d_in[2];
    const float* eb1   = (const float*)d_in[3];
    const float* ew2   = (const float*)d_in[4];
    const float* eb2   = (const float*)d_in[5];
    const float* gw    = (const float*)d_in[6];
    const float* gasrc = (const float*)d_in[7];
    const float* gadst = (const float*)d_in[8];
    const float* gbias = (const float*)d_in[9];
    const float* wq    = (const float*)d_in[10];
    const float* bq    = (const float*)d_in[11];
    const float* wk    = (const float*)d_in[12];
    const float* bk    = (const float*)d_in[13];
    const float* wv    = (const float*)d_in[14];
    const float* bv    = (const float*)d_in[15];
    const float* wo    = (const float*)d_in[16];
    const float* bo    = (const float*)d_in[17];
    const float* ln1g  = (const float*)d_in[18];
    const float* ln1b  = (const float*)d_in[19];
    const float* ln2g  = (const float*)d_in[20];
    const float* ln2b  = (const float*)d_in[21];
    const float* w1    = (const float*)d_in[22];
    const float* b1    = (const float*)d_in[23];
    const float* w2    = (const float*)d_in[24];
    const float* b2    = (const float*)d_in[25];

    const int E = in_sizes[1] / 2;
    const int* esrc = ei;
    const int* edst = ei + E;

    char* p = (char*)d_ws;
    auto alloc = [&](size_t bytes) -> void* {
        void* r = (void*)p;
        p += (bytes + 255) & ~(size_t)255;
        return r;
    };
    u16* xb    = (u16*)alloc(4096 * 256 * 2);
    u16* ew1t  = (u16*)alloc(128 * 256 * 2);
    u16* ew2t  = (u16*)alloc(128 * 128 * 2);
    u16* gwt   = (u16*)alloc(128 * 128 * 2);
    u16* wqkvt = (u16*)alloc(2 * 384 * 128 * 2);
    float* bqkv = (float*)alloc(2 * 384 * 4);
    u16* wot   = (u16*)alloc(2 * 128 * 128 * 2);
    u16* w1t   = (u16*)alloc(2 * 2048 * 128 * 2);
    u16* w2t   = (u16*)alloc(2 * 128 * 2048 * 2);
    u16* h1b   = (u16*)alloc(4096 * 128 * 2);
    u16* hb    = (u16*)alloc(4096 * 128 * 2);
    float* hh  = (float*)alloc(4096 * 128 * 4);
    float* ansrc = (float*)alloc(4096 * 2 * 4);
    float* andst = (float*)alloc(4096 * 2 * 4);
    int* counts    = (int*)alloc(4096 * 4);
    int* row_start = (int*)alloc(4097 * 4);
    int* cursor    = (int*)alloc(4096 * 4);
    int* csr_src   = (int*)alloc((size_t)E * 4);
    float* y32 = (float*)alloc(4096 * 128 * 4);
    u16* yb    = (u16*)alloc(4096 * 128 * 2);
    u16* qkvb  = (u16*)alloc((size_t)4096 * 256 * 2);   // Q,K only (pitch 256)
    u16* vtb   = (u16*)alloc(4096 * 128 * 2);           // V transposed [128][4096]
    u16* attnb = (u16*)alloc(4096 * 128 * 2);
    float* po  = (float*)alloc((size_t)64 * 4 * 8 * 64 * 32 * 4);
    float* pm  = (float*)alloc(64 * 4 * 8 * 64 * 4);
    float* pl  = (float*)alloc(64 * 4 * 8 * 64 * 4);
    float* proj32 = (float*)alloc(4096 * 128 * 4);
    u16* ff1b  = (u16*)alloc((size_t)4096 * 2048 * 2);
    float* ff2part = (float*)alloc((size_t)8 * 4096 * 128 * 4);

    // ---- prep ----
    prep_kernel<<<433, 256, 0, stream>>>(x, ew1, ew2, gw, wq, wk, wv, wo, w1, w2,
                                         bq, bk, bv,
                                         xb, ew1t, ew2t, gwt, wqkvt, bqkv, wot, w1t, w2t);

    // ---- encoder MLP ----
    gemm_bf16<<<dim3(64, 2), 256, 0, stream>>>(xb, ew1t, eb1, nullptr, h1b, nullptr, nullptr, 4096, 128, 256, 1, 256, 128);
    gemm_bf16<<<dim3(64, 2), 256, 0, stream>>>(h1b, ew2t, eb2, nullptr, hb, nullptr, nullptr, 4096, 128, 128, 0, 128, 128);

    // ---- GAT ----
    gemm_bf16<<<dim3(64, 2), 256, 0, stream>>>(hb, gwt, nullptr, hh, nullptr, nullptr, nullptr, 4096, 128, 128, 0, 128, 128);
    gat_prep<<<4096, 128, 0, stream>>>(hh, gasrc, gadst, ansrc, andst);
    hipMemsetAsync(counts, 0, 4096 * sizeof(int), stream);
    count_edges<<<(E + 255) / 256, 256, 0, stream>>>(edst, counts, E);
    scan_kernel<<<1, 1024, 0, stream>>>(counts, row_start, cursor);
    scatter_edges<<<(E + 255) / 256, 256, 0, stream>>>(esrc, edst, cursor, csr_src, E);
    gat_aggregate<<<4096, 256, 0, stream>>>(row_start, csr_src, ansrc, andst, hh, gbias, y32, yb);

    // ---- transformer layers ----
    for (int l = 0; l < 2; l++) {
        gemm_bf16<<<dim3(64, 6), 256, 0, stream>>>(yb, wqkvt + l * 49152, bqkv + l * 384, nullptr, qkvb, nullptr, vtb, 4096, 384, 128, 0, 128, 256);
        flash_attn_part<<<dim3(64, 4, 8), 256, 0, stream>>>(qkvb, qkvb + 128, vtb, po, pm, pl);
        attn_combine<<<dim3(64, 4), 256, 0, stream>>>(po, pm, pl, attnb);
        gemm_bf16<<<dim3(64, 2), 256, 0, stream>>>(attnb, wot + l * 16384, bo + l * 128, proj32, nullptr, nullptr, nullptr, 4096, 128, 128, 0, 128, 128);
        add_ln<<<4096, 128, 0, stream>>>(y32, proj32, ln1g + l * 128, ln1b + l * 128, y32, yb);
        gemm_bf16<<<dim3(64, 32), 256, 0, stream>>>(yb, w1t + (size_t)l * 262144, b1 + l * 2048, nullptr, ff1b, nullptr, nullptr, 4096, 2048, 128, 1, 128, 2048);
        gemm_bf16<<<dim3(64, 2, 8), 256, 0, stream>>>(ff1b, w2t + (size_t)l * 262144, nullptr, nullptr, nullptr, ff2part, nullptr, 4096, 128, 2048, 0, 256, 128);
        float* outp = (l == 1) ? (float*)d_out : y32;
        add_ln8<<<4096, 128, 0, stream>>>(y32, ff2part, b2 + l * 128, ln2g + l * 128, ln2b + l * 128, outp, yb);
    }
}